// Round 1
// baseline (534.057 us; speedup 1.0000x reference)
//
#include <hip/hip_runtime.h>

typedef __bf16 bf16;
typedef bf16 bf16x8 __attribute__((ext_vector_type(8)));
typedef bf16 bf16x4 __attribute__((ext_vector_type(4)));
typedef float f32x4 __attribute__((ext_vector_type(4)));

#define C_DIM 1024
#define T_DIM 2048
#define B_DIM 4
#define H_DIM 4096

// ---------------------------------------------------------------------------
// async global -> LDS, 16B per lane. LDS dest is wave-uniform base + lane*16.
// ---------------------------------------------------------------------------
__device__ inline void gld_lds16(const bf16* g, bf16* l) {
    __builtin_amdgcn_global_load_lds(
        (const __attribute__((address_space(1))) unsigned int*)g,
        (__attribute__((address_space(3))) unsigned int*)l,
        16, 0, 0);
}

// fast tanh-gelu: u * sigmoid(1.5957692*u + 0.07135481*u^3)
__device__ inline float fast_gelu(float u) {
    float k2 = 1.5957691216057308f * u + 0.07135480895843475f * u * u * u;
    float t = __expf(-k2);
    return u * __builtin_amdgcn_rcpf(1.0f + t);
}

// ---------------------------------------------------------------------------
// 8-phase 256-row-tile GEMM:  C[M,N] = alpha * A[M,K] @ Bt[N,K]^T (+bias)(+gelu|+resid)
//
// BM=256, BN in {256,128}, BK=64, 8 waves (wm 2 x wn 4), 512 threads.
// MFMA 16x16x32 bf16; per wave 8 x FN fragments (FN = BN/64).
// LDS: A as [2 buf][2 kslice][256 rows][32 k] bf16 (64KB), B likewise
// ([2][2][BN][32]).  Row stride 64B => each wave64 frag ds_read_b128 covers
// 16 whole rows = contiguous 1KB -> bank-conflict-free, no swizzle needed,
// and global_load_lds dest stays linear (lane i -> base + 16*i).
//
// Schedule per 2 K-tiles (8 phases). Phase = { ds_read frags | issue 1
// half-tile stage | barrier | setprio(1) MFMA x(4*FN) setprio(0) | [vmcnt]
// | barrier }.  Counted vmcnt (6 for BN=256, 4 for BN=128) once per K-tile
// keeps 3 half-tiles in flight; never drains to 0 in steady state.
// Each LDS half-slot is restaged in the phase right after its last read:
//   p1 reads Bk0/Ak0(rh0)   stages A-ks1 of t+1
//   p2 reads Ak0(rh1)       stages B-ks0 of t+2   (Bk0 of t read-done @p1)
//   p3 reads Bk1/Ak1(rh0)   stages A-ks0 of t+2   (Ak0 done @p2)
//   p4 reads Ak1(rh1)       stages B-ks1 of t+2   (Bk1 done @p3), vmcnt
//   p5..p8 same for tile t+1 (staging tile t+2 ks1 / tile t+3).
// Prologue stages 7 halves (tile0 all, tile1 Bk0/Ak0/Bk1) then vmcnt leaves
// exactly tile1's 3 halves in flight.
// ---------------------------------------------------------------------------
template <int EPI, typename OutT, int BN>
__launch_bounds__(512, 2)
__global__ void gemm8p(const bf16* __restrict__ A, int lda, long long sA,
                       const bf16* __restrict__ Bt, int ldb, long long sB,
                       OutT* __restrict__ Cout, int ldc, long long sC,
                       const float* __restrict__ bias,
                       const float* __restrict__ resid, long long sR,
                       float alpha, int K) {
    constexpr int FN = BN / 64;   // col fragments per wave (4 or 2)
    constexpr int BQ = BN / 128;  // gld_lds issues per B half (2 or 1)

    const int z = blockIdx.z;
    A += (long long)z * sA;
    Bt += (long long)z * sB;
    Cout += (long long)z * sC;
    if (resid) resid += (long long)z * sR;

    const int rowBase = blockIdx.x * 256;
    const int colBase = blockIdx.y * BN;

    __shared__ __align__(16) bf16 As[2 * 2 * 256 * 32];
    __shared__ __align__(16) bf16 Bs[2 * 2 * BN * 32];

    const int tid = threadIdx.x;
    const int w = tid >> 6;
    const int lane = tid & 63;
    const int wm = w >> 2, wn = w & 3;       // 2 x 4 wave grid
    const int lr = lane & 15, lc = lane >> 4;

    // staging: lane covers (row = tid>>2, 16B k-chunk = tid&3) of a 128-row slab
    const bf16* Ag = A + (size_t)(rowBase + (tid >> 2)) * lda + (tid & 3) * 8;
    const bf16* Bg = Bt + (size_t)(colBase + (tid >> 2)) * ldb + (tid & 3) * 8;
    const size_t ldaL = (size_t)lda, ldbL = (size_t)ldb;
    bf16* AsW = As + w * 512;   // wave slice inside each 4096-elem slab
    bf16* BsW = Bs + w * 512;

    // fragment read bases (element offsets)
    const int aBase = wm * 4096 + lr * 32 + lc * 8;        // + reg*8192 + rh*2048 + i*512
    const int bBase = wn * (FN * 512) + lr * 32 + lc * 8;  // + reg*(BN*32) + j*512

#define STAGE_A(buf, ks, tau) do {                                         \
        const bf16* _g = Ag + (size_t)(tau) * 64 + (ks) * 32;              \
        bf16* _l = AsW + ((buf) * 2 + (ks)) * 8192;                        \
        gld_lds16(_g, _l);                                                 \
        gld_lds16(_g + 128 * ldaL, _l + 4096);                             \
    } while (0)

#define STAGE_B(buf, ks, tau) do {                                         \
        const bf16* _g = Bg + (size_t)(tau) * 64 + (ks) * 32;              \
        bf16* _l = BsW + ((buf) * 2 + (ks)) * (BN * 32);                   \
        gld_lds16(_g, _l);                                                 \
        if constexpr (BQ == 2) gld_lds16(_g + 128 * ldbL, _l + 4096);      \
    } while (0)

#define LOAD_A(buf, ks, rh) do {                                           \
        _Pragma("unroll")                                                  \
        for (int i = 0; i < 4; i++)                                        \
            af[i] = *(const bf16x8*)(As + aBase + ((buf) * 2 + (ks)) * 8192 \
                                     + (rh) * 2048 + i * 512);             \
    } while (0)

#define LOAD_B(dst, buf, ks) do {                                          \
        _Pragma("unroll")                                                  \
        for (int j = 0; j < FN; j++)                                       \
            dst[j] = *(const bf16x8*)(Bs + bBase + ((buf) * 2 + (ks)) * (BN * 32) \
                                      + j * 512);                          \
    } while (0)

#define MMA(rh, bfr) do {                                                  \
        __builtin_amdgcn_s_setprio(1);                                     \
        _Pragma("unroll")                                                  \
        for (int i = 0; i < 4; i++)                                        \
            _Pragma("unroll")                                              \
            for (int j = 0; j < FN; j++)                                   \
                acc[(rh) * 4 + i][j] = __builtin_amdgcn_mfma_f32_16x16x32_bf16( \
                    af[i], bfr[j], acc[(rh) * 4 + i][j], 0, 0, 0);         \
        __builtin_amdgcn_s_setprio(0);                                     \
    } while (0)

#define BAR() do { __builtin_amdgcn_s_barrier(); __builtin_amdgcn_sched_barrier(0); } while (0)

#define VMW_STEADY() do {                                                  \
        if constexpr (BN == 256) asm volatile("s_waitcnt vmcnt(6)" ::: "memory"); \
        else                     asm volatile("s_waitcnt vmcnt(4)" ::: "memory"); \
    } while (0)
#define VMW0() asm volatile("s_waitcnt vmcnt(0)" ::: "memory")

    f32x4 acc[8][FN] = {};
    bf16x8 af[4], b0[FN], b1[FN];

    const int NT = K >> 6;  // K-tiles of 64; always even here (K in {1024,2048,4096})

    // ---- prologue: tile0 fully, tile1 Bk0/Ak0/Bk1 (Ak1 comes at p1) ----
    STAGE_B(0, 0, 0);
    STAGE_A(0, 0, 0);
    STAGE_B(0, 1, 0);
    STAGE_A(0, 1, 0);
    STAGE_B(1, 0, 1);
    STAGE_A(1, 0, 1);
    STAGE_B(1, 1, 1);
    VMW_STEADY();   // tile0 landed; tile1's 3 halves stay in flight
    BAR();

    for (int t = 0; t < NT; t += 2) {
        const bool more2 = (t + 2 < NT);

        // ================= K-tile t (buf 0) =================
        // p1: (ks0, rh0)
        LOAD_A(0, 0, 0); LOAD_B(b0, 0, 0);
        STAGE_A(1, 1, t + 1);
        BAR(); MMA(0, b0); BAR();
        // p2: (ks0, rh1)
        LOAD_A(0, 0, 1);
        if (more2) STAGE_B(0, 0, t + 2);
        BAR(); MMA(1, b0); BAR();
        // p3: (ks1, rh0)
        LOAD_A(0, 1, 0); LOAD_B(b1, 0, 1);
        if (more2) STAGE_A(0, 0, t + 2);
        BAR(); MMA(0, b1); BAR();
        // p4: (ks1, rh1)  + vmcnt guaranteeing tile t+1 fully landed
        LOAD_A(0, 1, 1);
        if (more2) STAGE_B(0, 1, t + 2);
        BAR(); MMA(1, b1);
        if (more2) VMW_STEADY(); else VMW0();
        BAR();

        // ================= K-tile t+1 (buf 1) =================
        // p5: (ks0, rh0)
        LOAD_A(1, 0, 0); LOAD_B(b0, 1, 0);
        if (more2) STAGE_A(0, 1, t + 2);
        BAR(); MMA(0, b0); BAR();
        // p6: (ks0, rh1)
        LOAD_A(1, 0, 1);
        if (more2) STAGE_B(1, 0, t + 3);
        BAR(); MMA(1, b0); BAR();
        // p7: (ks1, rh0)
        LOAD_A(1, 1, 0); LOAD_B(b1, 1, 1);
        if (more2) STAGE_A(1, 0, t + 3);
        BAR(); MMA(0, b1); BAR();
        // p8: (ks1, rh1)  + vmcnt guaranteeing tile t+2 fully landed
        LOAD_A(1, 1, 1);
        if (more2) STAGE_B(1, 1, t + 3);
        BAR(); MMA(1, b1);
        if (more2) VMW_STEADY();
        BAR();
    }

#undef STAGE_A
#undef STAGE_B
#undef LOAD_A
#undef LOAD_B
#undef MMA
#undef BAR
#undef VMW_STEADY
#undef VMW0

    // ---- epilogue. C/D layout (16x16x32): col = lane&15, row = (lane>>4)*4 + reg ----
    float bval[FN];
#pragma unroll
    for (int j = 0; j < FN; j++)
        bval[j] = bias ? bias[colBase + wn * (FN * 16) + j * 16 + lr] : 0.0f;

#pragma unroll
    for (int fi = 0; fi < 8; fi++) {
        const int row = rowBase + wm * 128 + fi * 16 + lc * 4;
#pragma unroll
        for (int fj = 0; fj < FN; fj++) {
            const int col = colBase + wn * (FN * 16) + fj * 16 + lr;
#pragma unroll
            for (int r = 0; r < 4; r++) {
                float v = acc[fi][fj][r] * alpha + bval[fj];
                if constexpr (EPI == 1) v = fast_gelu(v);
                if constexpr (EPI == 2) v += resid[(size_t)(row + r) * ldc + col];
                Cout[(size_t)(row + r) * ldc + col] = (OutT)v;
            }
        }
    }
}

// ---------------------------------------------------------------------------
// LayerNorm over last dim (C=1024), fp32 in -> bf16 out. One block per row.
// ---------------------------------------------------------------------------
__launch_bounds__(256)
__global__ void ln_kernel(const float* __restrict__ x, const float* __restrict__ g,
                          const float* __restrict__ b, bf16* __restrict__ out) {
    __shared__ float red[4];
    const int row = blockIdx.x;
    const int tid = threadIdx.x;
    const float4* xr = (const float4*)(x + (size_t)row * C_DIM);
    float4 v = xr[tid];
    float s = v.x + v.y + v.z + v.w;
#pragma unroll
    for (int m = 32; m; m >>= 1) s += __shfl_xor(s, m, 64);
    if ((tid & 63) == 0) red[tid >> 6] = s;
    __syncthreads();
    const float mu = (red[0] + red[1] + red[2] + red[3]) * (1.0f / C_DIM);
    const float dx = v.x - mu, dy = v.y - mu, dz = v.z - mu, dw = v.w - mu;
    float q = dx * dx + dy * dy + dz * dz + dw * dw;
#pragma unroll
    for (int m = 32; m; m >>= 1) q += __shfl_xor(q, m, 64);
    __syncthreads();
    if ((tid & 63) == 0) red[tid >> 6] = q;
    __syncthreads();
    const float var = (red[0] + red[1] + red[2] + red[3]) * (1.0f / C_DIM);
    const float rs = rsqrtf(var + 1e-5f);
    const float4 gg = ((const float4*)g)[tid];
    const float4 bb = ((const float4*)b)[tid];
    bf16x4 o;
    o[0] = (bf16)(dx * rs * gg.x + bb.x);
    o[1] = (bf16)(dy * rs * gg.y + bb.y);
    o[2] = (bf16)(dz * rs * gg.z + bb.z);
    o[3] = (bf16)(dw * rs * gg.w + bb.w);
    ((bf16x4*)(out + (size_t)row * C_DIM))[tid] = o;
}

// ---------------------------------------------------------------------------
// Row softmax: S row (T=2048 bf16) -> P row (bf16). One block per row.
// ---------------------------------------------------------------------------
__launch_bounds__(256)
__global__ void softmax_kernel(const bf16* __restrict__ S, bf16* __restrict__ P) {
    __shared__ float red[4];
    const size_t base = (size_t)blockIdx.x * T_DIM;
    const int tid = threadIdx.x;
    bf16x8 sv = ((const bf16x8*)(S + base))[tid];
    float e[8];
#pragma unroll
    for (int i = 0; i < 8; i++) e[i] = (float)sv[i];
    float mx = e[0];
#pragma unroll
    for (int i = 1; i < 8; i++) mx = fmaxf(mx, e[i]);
#pragma unroll
    for (int m = 32; m; m >>= 1) mx = fmaxf(mx, __shfl_xor(mx, m, 64));
    if ((tid & 63) == 0) red[tid >> 6] = mx;
    __syncthreads();
    mx = fmaxf(fmaxf(red[0], red[1]), fmaxf(red[2], red[3]));
    float s = 0.0f;
#pragma unroll
    for (int i = 0; i < 8; i++) {
        e[i] = __expf(e[i] - mx);
        s += e[i];
    }
#pragma unroll
    for (int m = 32; m; m >>= 1) s += __shfl_xor(s, m, 64);
    __syncthreads();
    if ((tid & 63) == 0) red[tid >> 6] = s;
    __syncthreads();
    const float inv = 1.0f / (red[0] + red[1] + red[2] + red[3]);
    bf16x8 p;
#pragma unroll
    for (int i = 0; i < 8; i++) p[i] = (bf16)(e[i] * inv);
    ((bf16x8*)(P + base))[tid] = p;
}

// ---------------------------------------------------------------------------
// Merged transpose+convert for all 4 weight matrices (fp32 [R,Cc] -> bf16 [Cc,R]).
// ---------------------------------------------------------------------------
__global__ void transpose_f2b_all(const float* __restrict__ s0, bf16* __restrict__ d0,
                                  const float* __restrict__ s1, bf16* __restrict__ d1,
                                  const float* __restrict__ s2, bf16* __restrict__ d2,
                                  const float* __restrict__ s3, bf16* __restrict__ d3) {
    __shared__ float tile[32][33];
    int id = blockIdx.x;
    const float* src;
    bf16* dst;
    int R, Cc, local;
    if (id < 3072)       { src = s0; dst = d0; R = 1024; Cc = 3072; local = id; }
    else if (id < 4096)  { src = s1; dst = d1; R = 1024; Cc = 1024; local = id - 3072; }
    else if (id < 8192)  { src = s2; dst = d2; R = 1024; Cc = 4096; local = id - 4096; }
    else                 { src = s3; dst = d3; R = 4096; Cc = 1024; local = id - 8192; }
    const int tilesX = Cc >> 5;
    const int bx = (local % tilesX) * 32;
    const int by = (local / tilesX) * 32;
    const int tx = threadIdx.x, ty = threadIdx.y;
    for (int i = ty; i < 32; i += 8)
        tile[i][tx] = src[(size_t)(by + i) * Cc + bx + tx];
    __syncthreads();
    for (int i = ty; i < 32; i += 8)
        dst[(size_t)(bx + i) * R + by + tx] = (bf16)tile[tx][i];
}

// Transpose bf16 [R, Cc] (ld=ldsrc) -> bf16 [Cc, R] (ld=R), batched via z.
__global__ void transpose_b2b(const bf16* __restrict__ src, int ldsrc, long long sstride,
                              bf16* __restrict__ dst, long long dstride, int R) {
    __shared__ bf16 tile[32][33];
    src += (long long)blockIdx.z * sstride;
    dst += (long long)blockIdx.z * dstride;
    const int bx = blockIdx.x * 32;
    const int by = blockIdx.y * 32;
    const int tx = threadIdx.x, ty = threadIdx.y;
    for (int i = ty; i < 32; i += 8)
        tile[i][tx] = src[(size_t)(by + i) * ldsrc + bx + tx];
    __syncthreads();
    for (int i = ty; i < 32; i += 8)
        dst[(size_t)(bx + i) * R + by + tx] = tile[tx][i];
}

// ---------------------------------------------------------------------------
extern "C" void kernel_launch(void* const* d_in, const int* in_sizes, int n_in,
                              void* d_out, int out_size, void* d_ws, size_t ws_size,
                              hipStream_t stream) {
    const float* x      = (const float*)d_in[0];
    const float* ln1_g  = (const float*)d_in[1];
    const float* ln1_b  = (const float*)d_in[2];
    const float* w_attn = (const float*)d_in[3];
    const float* b_attn = (const float*)d_in[4];
    const float* w_proj = (const float*)d_in[5];
    const float* b_proj = (const float*)d_in[6];
    const float* ln2_g  = (const float*)d_in[7];
    const float* ln2_b  = (const float*)d_in[8];
    const float* w_fc   = (const float*)d_in[9];
    const float* b_fc   = (const float*)d_in[10];
    const float* w_mlp  = (const float*)d_in[11];
    const float* b_mlp  = (const float*)d_in[12];
    float* out = (float*)d_out;

    const int M = B_DIM * T_DIM;  // 8192

    char* base = (char*)d_ws;
    size_t off = 0;
    auto alloc = [&](size_t bytes) -> char* {
        char* p = base + off;
        off += (bytes + 255) & ~(size_t)255;
        return p;
    };
    bf16* wT_attn = (bf16*)alloc((size_t)3072 * 1024 * 2);
    bf16* wT_proj = (bf16*)alloc((size_t)1024 * 1024 * 2);
    bf16* wT_fc   = (bf16*)alloc((size_t)4096 * 1024 * 2);
    bf16* wT_mlp  = (bf16*)alloc((size_t)1024 * 4096 * 2);
    bf16* h       = (bf16*)alloc((size_t)M * 1024 * 2);        // h1, reused as h2
    bf16* qkv     = (bf16*)alloc((size_t)M * 3072 * 2);
    bf16* vT      = (bf16*)alloc((size_t)B_DIM * 1024 * 2048 * 2);
    bf16* S       = (bf16*)alloc((size_t)B_DIM * 2048 * 2048 * 2);
    bf16* P       = (bf16*)alloc((size_t)B_DIM * 2048 * 2048 * 2);
    bf16* y       = (bf16*)alloc((size_t)M * 1024 * 2);
    float* x2     = (float*)alloc((size_t)M * 1024 * 4);
    bf16* act     = (bf16*)S;  // alias: S+P dead after PV; 67MB needed, S+P = 67MB

    const dim3 tb(32, 8);

    // weight transpose+convert, all 4 in one launch
    transpose_f2b_all<<<12288, tb, 0, stream>>>(w_attn, wT_attn, w_proj, wT_proj,
                                                w_fc, wT_fc, w_mlp, wT_mlp);

    // h = LN1(x)
    ln_kernel<<<M, 256, 0, stream>>>(x, ln1_g, ln1_b, h);

    // qkv = h @ w_attn + b_attn   [8192, 3072]   (BN=128 -> 768 blocks = 3 full waves)
    gemm8p<0, bf16, 128><<<dim3(32, 24, 1), 512, 0, stream>>>(
        h, 1024, 0, wT_attn, 1024, 0, qkv, 3072, 0, b_attn, nullptr, 0, 1.0f, 1024);

    // vT[b] = v[b]^T   (v = qkv cols [2C,3C))
    transpose_b2b<<<dim3(1024 / 32, 2048 / 32, B_DIM), tb, 0, stream>>>(
        qkv + 2 * C_DIM, 3072, (long long)T_DIM * 3072, vT, (long long)C_DIM * T_DIM, T_DIM);

    // S[b] = q[b] @ k[b]^T * (1/32)   [2048, 2048] bf16   (256 blocks)
    gemm8p<0, bf16, 256><<<dim3(8, 8, B_DIM), 512, 0, stream>>>(
        qkv, 3072, (long long)T_DIM * 3072,
        qkv + C_DIM, 3072, (long long)T_DIM * 3072,
        S, 2048, (long long)T_DIM * T_DIM, nullptr, nullptr, 0, 0.03125f, 1024);

    // P = softmax(S) rows
    softmax_kernel<<<B_DIM * T_DIM, 256, 0, stream>>>(S, P);

    // y[b] = P[b] @ v[b]   [2048, 1024] bf16   (BN=128 -> 256 blocks)
    gemm8p<0, bf16, 128><<<dim3(8, 8, B_DIM), 512, 0, stream>>>(
        P, 2048, (long long)T_DIM * T_DIM,
        vT, 2048, (long long)C_DIM * T_DIM,
        y, 1024, (long long)T_DIM * C_DIM, nullptr, nullptr, 0, 1.0f, 2048);

    // x2 = y @ w_proj + b_proj + x   [8192, 1024] fp32   (BN=128 -> 256 blocks)
    gemm8p<2, float, 128><<<dim3(32, 8, 1), 512, 0, stream>>>(
        y, 1024, 0, wT_proj, 1024, 0, x2, 1024, 0, b_proj, x, 0, 1.0f, 1024);

    // h2 = LN2(x2)  (reuse h buffer)
    ln_kernel<<<M, 256, 0, stream>>>(x2, ln2_g, ln2_b, h);

    // act = gelu(h2 @ w_fc + b_fc)   [8192, 4096] bf16   (512 blocks = 2 full waves)
    gemm8p<1, bf16, 256><<<dim3(32, 16, 1), 512, 0, stream>>>(
        h, 1024, 0, wT_fc, 1024, 0, act, 4096, 0, b_fc, nullptr, 0, 1.0f, 1024);

    // out = act @ w_mlp_proj + b_mlp_proj + x2   [8192, 1024] fp32   (BN=128 -> 256 blocks)
    gemm8p<2, float, 128><<<dim3(32, 8, 1), 512, 0, stream>>>(
        act, 4096, 0, wT_mlp, 4096, 0, out, 1024, 0, b_mlp, x2, 0, 1.0f, 4096);
}

// Round 2
// 516.162 us; speedup vs baseline: 1.0347x; 1.0347x over previous
//
#include <hip/hip_runtime.h>

typedef __bf16 bf16;
typedef bf16 bf16x8 __attribute__((ext_vector_type(8)));
typedef bf16 bf16x4 __attribute__((ext_vector_type(4)));
typedef float f32x4 __attribute__((ext_vector_type(4)));

#define C_DIM 1024
#define T_DIM 2048
#define B_DIM 4
#define H_DIM 4096

// ---------------------------------------------------------------------------
// async global -> LDS, 16B per lane. LDS dest is wave-uniform base + lane*16.
// ---------------------------------------------------------------------------
__device__ inline void gld_lds16(const bf16* g, bf16* l) {
    __builtin_amdgcn_global_load_lds(
        (const __attribute__((address_space(1))) unsigned int*)g,
        (__attribute__((address_space(3))) unsigned int*)l,
        16, 0, 0);
}

// fast tanh-gelu: u * sigmoid(1.5957692*u + 0.07135481*u^3)
__device__ inline float fast_gelu(float u) {
    float k2 = 1.5957691216057308f * u + 0.07135480895843475f * u * u * u;
    float t = __expf(-k2);
    return u * __builtin_amdgcn_rcpf(1.0f + t);
}

// ---------------------------------------------------------------------------
// 8/4-phase 256-row-tile GEMM:  C = alpha * A[M,K] @ Bt[N,K]^T (+bias)(+gelu|+resid)
//
// BM=256, BN in {256,128}, BK=64, 8 waves, 512 threads, MFMA 16x16x32 bf16.
//   BN=256: waves 2x4 (wave tile 128x64), 4 phases/K-tile (ks x rh), 16 MFMA/phase
//   BN=128: waves 4x2 (wave tile  64x64), 2 phases/K-tile (ks),      16 MFMA/phase
//
// LDS: A [2 buf][2 ks][256 rows][32 k] bf16 (64KB); B [2][2][BN][32].
// XOR swizzle (bank-conflict fix, derived for quarter-wave b128 service):
//   16B chunk c of row r stored at slot c ^ ((r>>1)&3).
//   - read side: chunk = lc ^ ((lr>>1)&3) -> per-lane constant (free);
//     quarter lanes then cover all 8 bank-groups exactly 2x -> conflict-free.
//   - write side: gld_lds dest stays LINEAR (lane*16); the global SOURCE
//     chunk is pre-swizzled: (tid&3) ^ ((tid>>3)&3) (rule: both-sides).
//
// Counted vmcnt (never 0 in steady state) keeps ~1.5 K-tiles of loads in
// flight across barriers; each LDS slot restaged in the phase right after
// its last read. BN=256: vmcnt(6) at phases 4,8. BN=128: vmcnt(3) at 2,4.
// ---------------------------------------------------------------------------
template <int EPI, typename OutT, int BN>
__launch_bounds__(512, 2)
__global__ void gemm8p(const bf16* __restrict__ A, int lda, long long sA,
                       const bf16* __restrict__ Bt, int ldb, long long sB,
                       OutT* __restrict__ Cout, int ldc, long long sC,
                       const float* __restrict__ bias,
                       const float* __restrict__ resid, long long sR,
                       float alpha, int K) {
    constexpr int BQ = BN / 128;            // gld_lds issues per B half-slab
    constexpr int FM = (BN == 256) ? 8 : 4; // row fragments per wave
    constexpr int AW = (BN == 256) ? 128 : 64;  // rows per wave strip

    const int z = blockIdx.z;
    A += (long long)z * sA;
    Bt += (long long)z * sB;
    Cout += (long long)z * sC;
    if (resid) resid += (long long)z * sR;

    const int rowBase = blockIdx.x * 256;
    const int colBase = blockIdx.y * BN;

    __shared__ __align__(16) bf16 As[2 * 2 * 256 * 32];
    __shared__ __align__(16) bf16 Bs[2 * 2 * BN * 32];

    const int tid = threadIdx.x;
    const int w = tid >> 6;
    const int lane = tid & 63;
    const int wm = (BN == 256) ? (w >> 2) : (w >> 1);
    const int wn = (BN == 256) ? (w & 3) : (w & 1);
    const int lr = lane & 15, lc = lane >> 4;

    // staging: lane covers (row = tid>>2, swizzled 16B chunk) of a 128-row slab
    const int gchunk = (tid & 3) ^ ((tid >> 3) & 3);
    const bf16* Ag = A + (size_t)(rowBase + (tid >> 2)) * lda + gchunk * 8;
    const bf16* Bg = Bt + (size_t)(colBase + (tid >> 2)) * ldb + gchunk * 8;
    const size_t ldaL = (size_t)lda, ldbL = (size_t)ldb;
    bf16* AsW = As + w * 512;   // wave slice inside each staged 8KB half-slab
    bf16* BsW = Bs + w * 512;

    // fragment read bases (element offsets); read chunk XOR folds into base
    const int rchunk = lc ^ ((lr >> 1) & 3);
    const int aBase = wm * (AW * 32) + lr * 32 + rchunk * 8;  // + slab/rh/i terms
    const int bBase = wn * 2048 + lr * 32 + rchunk * 8;       // + slab/j terms

#define STAGE_A(buf, ks, tau) do {                                         \
        const bf16* _g = Ag + (size_t)(tau) * 64 + (ks) * 32;              \
        bf16* _l = AsW + ((buf) * 2 + (ks)) * 8192;                        \
        gld_lds16(_g, _l);                                                 \
        gld_lds16(_g + 128 * ldaL, _l + 4096);                             \
    } while (0)

#define STAGE_B(buf, ks, tau) do {                                         \
        const bf16* _g = Bg + (size_t)(tau) * 64 + (ks) * 32;              \
        bf16* _l = BsW + ((buf) * 2 + (ks)) * (BN * 32);                   \
        gld_lds16(_g, _l);                                                 \
        if constexpr (BQ == 2) gld_lds16(_g + 128 * ldbL, _l + 4096);      \
    } while (0)

#define LOAD_A(buf, ks, rh) do {                                           \
        _Pragma("unroll")                                                  \
        for (int i = 0; i < 4; i++)                                        \
            af[i] = *(const bf16x8*)(As + aBase + ((buf) * 2 + (ks)) * 8192 \
                                     + (rh) * 2048 + i * 512);             \
    } while (0)

#define LOAD_B(dst, buf, ks) do {                                          \
        _Pragma("unroll")                                                  \
        for (int j = 0; j < 4; j++)                                        \
            dst[j] = *(const bf16x8*)(Bs + bBase + ((buf) * 2 + (ks)) * (BN * 32) \
                                      + j * 512);                          \
    } while (0)

#define MMA(rh, bfr) do {                                                  \
        __builtin_amdgcn_s_setprio(1);                                     \
        _Pragma("unroll")                                                  \
        for (int i = 0; i < 4; i++)                                        \
            _Pragma("unroll")                                              \
            for (int j = 0; j < 4; j++)                                    \
                acc[(rh) * 4 + i][j] = __builtin_amdgcn_mfma_f32_16x16x32_bf16( \
                    af[i], bfr[j], acc[(rh) * 4 + i][j], 0, 0, 0);         \
        __builtin_amdgcn_s_setprio(0);                                     \
    } while (0)

#define BAR() do { __builtin_amdgcn_s_barrier(); __builtin_amdgcn_sched_barrier(0); } while (0)
#define VMC(n) asm volatile("s_waitcnt vmcnt(" #n ")" ::: "memory")

    f32x4 acc[FM][4] = {};
    bf16x8 af[4], b0[4], b1[4];

    const int NT = K >> 6;  // K in {1024,2048,4096} -> NT even, >= 16

    if constexpr (BN == 256) {
        // ---- prologue: tile0 fully, tile1 Bk0/Ak0/Bk1 ----
        STAGE_B(0, 0, 0);
        STAGE_A(0, 0, 0);
        STAGE_B(0, 1, 0);
        STAGE_A(0, 1, 0);
        STAGE_B(1, 0, 1);
        STAGE_A(1, 0, 1);
        STAGE_B(1, 1, 1);
        VMC(6);
        BAR();

        for (int t = 0; t < NT; t += 2) {
            const bool more2 = (t + 2 < NT);
            // ===== K-tile t (buf 0) =====
            LOAD_A(0, 0, 0); LOAD_B(b0, 0, 0);
            STAGE_A(1, 1, t + 1);
            BAR(); MMA(0, b0); BAR();

            LOAD_A(0, 0, 1);
            if (more2) STAGE_B(0, 0, t + 2);
            BAR(); MMA(1, b0); BAR();

            LOAD_A(0, 1, 0); LOAD_B(b1, 0, 1);
            if (more2) STAGE_A(0, 0, t + 2);
            BAR(); MMA(0, b1); BAR();

            LOAD_A(0, 1, 1);
            if (more2) STAGE_B(0, 1, t + 2);
            BAR(); MMA(1, b1);
            if (more2) VMC(6); else VMC(0);
            BAR();

            // ===== K-tile t+1 (buf 1) =====
            LOAD_A(1, 0, 0); LOAD_B(b0, 1, 0);
            if (more2) STAGE_A(0, 1, t + 2);
            BAR(); MMA(0, b0); BAR();

            LOAD_A(1, 0, 1);
            if (more2) STAGE_B(1, 0, t + 3);
            BAR(); MMA(1, b0); BAR();

            LOAD_A(1, 1, 0); LOAD_B(b1, 1, 1);
            if (more2) STAGE_A(1, 0, t + 3);
            BAR(); MMA(0, b1); BAR();

            LOAD_A(1, 1, 1);
            if (more2) STAGE_B(1, 1, t + 3);
            BAR(); MMA(1, b1);
            if (more2) VMC(6);
            BAR();
        }
    } else {
        // ---- BN=128: 2 phases per K-tile, 16 MFMA each ----
        // prologue: tile0 fully, tile1 ks0
        STAGE_A(0, 0, 0);
        STAGE_B(0, 0, 0);
        STAGE_A(0, 1, 0);
        STAGE_B(0, 1, 0);
        STAGE_A(1, 0, 1);
        STAGE_B(1, 0, 1);
        VMC(3);   // tile0 landed; tile1-ks0 (3 loads) in flight
        BAR();

        for (int t = 0; t < NT; t += 2) {
            const bool more2 = (t + 2 < NT);
            // p1: tile t, ks0
            LOAD_A(0, 0, 0); LOAD_B(b0, 0, 0);
            STAGE_A(1, 1, t + 1); STAGE_B(1, 1, t + 1);
            BAR(); MMA(0, b0); BAR();
            // p2: tile t, ks1
            LOAD_A(0, 1, 0); LOAD_B(b1, 0, 1);
            if (more2) { STAGE_A(0, 0, t + 2); STAGE_B(0, 0, t + 2); }
            BAR(); MMA(0, b1);
            if (more2) VMC(3); else VMC(0);   // tile t+1 fully landed
            BAR();
            // p3: tile t+1, ks0
            LOAD_A(1, 0, 0); LOAD_B(b0, 1, 0);
            if (more2) { STAGE_A(0, 1, t + 2); STAGE_B(0, 1, t + 2); }
            BAR(); MMA(0, b0); BAR();
            // p4: tile t+1, ks1
            LOAD_A(1, 1, 0); LOAD_B(b1, 1, 1);
            if (more2) { STAGE_A(1, 0, t + 3); STAGE_B(1, 0, t + 3); }
            BAR(); MMA(0, b1);
            if (more2) VMC(3);                // tile t+2 fully landed
            BAR();
        }
    }

#undef STAGE_A
#undef STAGE_B
#undef LOAD_A
#undef LOAD_B
#undef MMA
#undef BAR
#undef VMC

    // ---- epilogue. C/D layout (16x16x32): col = lane&15, row = (lane>>4)*4 + reg ----
    float bval[4];
#pragma unroll
    for (int j = 0; j < 4; j++)
        bval[j] = bias ? bias[colBase + wn * 64 + j * 16 + lr] : 0.0f;

#pragma unroll
    for (int fi = 0; fi < FM; fi++) {
        const int row = rowBase + wm * AW + fi * 16 + lc * 4;
#pragma unroll
        for (int fj = 0; fj < 4; fj++) {
            const int col = colBase + wn * 64 + fj * 16 + lr;
#pragma unroll
            for (int r = 0; r < 4; r++) {
                float v = acc[fi][fj][r] * alpha + bval[fj];
                if constexpr (EPI == 1) v = fast_gelu(v);
                if constexpr (EPI == 2) v += resid[(size_t)(row + r) * ldc + col];
                Cout[(size_t)(row + r) * ldc + col] = (OutT)v;
            }
        }
    }
}

// ---------------------------------------------------------------------------
// LayerNorm over last dim (C=1024), fp32 in -> bf16 out. One block per row.
// ---------------------------------------------------------------------------
__launch_bounds__(256)
__global__ void ln_kernel(const float* __restrict__ x, const float* __restrict__ g,
                          const float* __restrict__ b, bf16* __restrict__ out) {
    __shared__ float red[4];
    const int row = blockIdx.x;
    const int tid = threadIdx.x;
    const float4* xr = (const float4*)(x + (size_t)row * C_DIM);
    float4 v = xr[tid];
    float s = v.x + v.y + v.z + v.w;
#pragma unroll
    for (int m = 32; m; m >>= 1) s += __shfl_xor(s, m, 64);
    if ((tid & 63) == 0) red[tid >> 6] = s;
    __syncthreads();
    const float mu = (red[0] + red[1] + red[2] + red[3]) * (1.0f / C_DIM);
    const float dx = v.x - mu, dy = v.y - mu, dz = v.z - mu, dw = v.w - mu;
    float q = dx * dx + dy * dy + dz * dz + dw * dw;
#pragma unroll
    for (int m = 32; m; m >>= 1) q += __shfl_xor(q, m, 64);
    __syncthreads();
    if ((tid & 63) == 0) red[tid >> 6] = q;
    __syncthreads();
    const float var = (red[0] + red[1] + red[2] + red[3]) * (1.0f / C_DIM);
    const float rs = rsqrtf(var + 1e-5f);
    const float4 gg = ((const float4*)g)[tid];
    const float4 bb = ((const float4*)b)[tid];
    bf16x4 o;
    o[0] = (bf16)(dx * rs * gg.x + bb.x);
    o[1] = (bf16)(dy * rs * gg.y + bb.y);
    o[2] = (bf16)(dz * rs * gg.z + bb.z);
    o[3] = (bf16)(dw * rs * gg.w + bb.w);
    ((bf16x4*)(out + (size_t)row * C_DIM))[tid] = o;
}

// ---------------------------------------------------------------------------
// Row softmax: S row (T=2048 bf16) -> P row (bf16). One block per row.
// ---------------------------------------------------------------------------
__launch_bounds__(256)
__global__ void softmax_kernel(const bf16* __restrict__ S, bf16* __restrict__ P) {
    __shared__ float red[4];
    const size_t base = (size_t)blockIdx.x * T_DIM;
    const int tid = threadIdx.x;
    bf16x8 sv = ((const bf16x8*)(S + base))[tid];
    float e[8];
#pragma unroll
    for (int i = 0; i < 8; i++) e[i] = (float)sv[i];
    float mx = e[0];
#pragma unroll
    for (int i = 1; i < 8; i++) mx = fmaxf(mx, e[i]);
#pragma unroll
    for (int m = 32; m; m >>= 1) mx = fmaxf(mx, __shfl_xor(mx, m, 64));
    if ((tid & 63) == 0) red[tid >> 6] = mx;
    __syncthreads();
    mx = fmaxf(fmaxf(red[0], red[1]), fmaxf(red[2], red[3]));
    float s = 0.0f;
#pragma unroll
    for (int i = 0; i < 8; i++) {
        e[i] = __expf(e[i] - mx);
        s += e[i];
    }
#pragma unroll
    for (int m = 32; m; m >>= 1) s += __shfl_xor(s, m, 64);
    __syncthreads();
    if ((tid & 63) == 0) red[tid >> 6] = s;
    __syncthreads();
    const float inv = 1.0f / (red[0] + red[1] + red[2] + red[3]);
    bf16x8 p;
#pragma unroll
    for (int i = 0; i < 8; i++) p[i] = (bf16)(e[i] * inv);
    ((bf16x8*)(P + base))[tid] = p;
}

// ---------------------------------------------------------------------------
// Merged transpose+convert for all 4 weight matrices (fp32 [R,Cc] -> bf16 [Cc,R]).
// ---------------------------------------------------------------------------
__global__ void transpose_f2b_all(const float* __restrict__ s0, bf16* __restrict__ d0,
                                  const float* __restrict__ s1, bf16* __restrict__ d1,
                                  const float* __restrict__ s2, bf16* __restrict__ d2,
                                  const float* __restrict__ s3, bf16* __restrict__ d3) {
    __shared__ float tile[32][33];
    int id = blockIdx.x;
    const float* src;
    bf16* dst;
    int R, Cc, local;
    if (id < 3072)       { src = s0; dst = d0; R = 1024; Cc = 3072; local = id; }
    else if (id < 4096)  { src = s1; dst = d1; R = 1024; Cc = 1024; local = id - 3072; }
    else if (id < 8192)  { src = s2; dst = d2; R = 1024; Cc = 4096; local = id - 4096; }
    else                 { src = s3; dst = d3; R = 4096; Cc = 1024; local = id - 8192; }
    const int tilesX = Cc >> 5;
    const int bx = (local % tilesX) * 32;
    const int by = (local / tilesX) * 32;
    const int tx = threadIdx.x, ty = threadIdx.y;
    for (int i = ty; i < 32; i += 8)
        tile[i][tx] = src[(size_t)(by + i) * Cc + bx + tx];
    __syncthreads();
    for (int i = ty; i < 32; i += 8)
        dst[(size_t)(bx + i) * R + by + tx] = (bf16)tile[tx][i];
}

// Transpose bf16 [R, Cc] (ld=ldsrc) -> bf16 [Cc, R] (ld=R), batched via z.
__global__ void transpose_b2b(const bf16* __restrict__ src, int ldsrc, long long sstride,
                              bf16* __restrict__ dst, long long dstride, int R) {
    __shared__ bf16 tile[32][33];
    src += (long long)blockIdx.z * sstride;
    dst += (long long)blockIdx.z * dstride;
    const int bx = blockIdx.x * 32;
    const int by = blockIdx.y * 32;
    const int tx = threadIdx.x, ty = threadIdx.y;
    for (int i = ty; i < 32; i += 8)
        tile[i][tx] = src[(size_t)(by + i) * ldsrc + bx + tx];
    __syncthreads();
    for (int i = ty; i < 32; i += 8)
        dst[(size_t)(bx + i) * R + by + tx] = tile[tx][i];
}

// ---------------------------------------------------------------------------
extern "C" void kernel_launch(void* const* d_in, const int* in_sizes, int n_in,
                              void* d_out, int out_size, void* d_ws, size_t ws_size,
                              hipStream_t stream) {
    const float* x      = (const float*)d_in[0];
    const float* ln1_g  = (const float*)d_in[1];
    const float* ln1_b  = (const float*)d_in[2];
    const float* w_attn = (const float*)d_in[3];
    const float* b_attn = (const float*)d_in[4];
    const float* w_proj = (const float*)d_in[5];
    const float* b_proj = (const float*)d_in[6];
    const float* ln2_g  = (const float*)d_in[7];
    const float* ln2_b  = (const float*)d_in[8];
    const float* w_fc   = (const float*)d_in[9];
    const float* b_fc   = (const float*)d_in[10];
    const float* w_mlp  = (const float*)d_in[11];
    const float* b_mlp  = (const float*)d_in[12];
    float* out = (float*)d_out;

    const int M = B_DIM * T_DIM;  // 8192

    char* base = (char*)d_ws;
    size_t off = 0;
    auto alloc = [&](size_t bytes) -> char* {
        char* p = base + off;
        off += (bytes + 255) & ~(size_t)255;
        return p;
    };
    bf16* wT_attn = (bf16*)alloc((size_t)3072 * 1024 * 2);
    bf16* wT_proj = (bf16*)alloc((size_t)1024 * 1024 * 2);
    bf16* wT_fc   = (bf16*)alloc((size_t)4096 * 1024 * 2);
    bf16* wT_mlp  = (bf16*)alloc((size_t)1024 * 4096 * 2);
    bf16* h       = (bf16*)alloc((size_t)M * 1024 * 2);        // h1, reused as h2
    bf16* qkv     = (bf16*)alloc((size_t)M * 3072 * 2);
    bf16* vT      = (bf16*)alloc((size_t)B_DIM * 1024 * 2048 * 2);
    bf16* S       = (bf16*)alloc((size_t)B_DIM * 2048 * 2048 * 2);
    bf16* P       = (bf16*)alloc((size_t)B_DIM * 2048 * 2048 * 2);
    bf16* y       = (bf16*)alloc((size_t)M * 1024 * 2);
    float* x2     = (float*)alloc((size_t)M * 1024 * 4);
    bf16* act     = (bf16*)S;  // alias: S+P dead after PV; 67MB needed, S+P = 67MB

    const dim3 tb(32, 8);

    // weight transpose+convert, all 4 in one launch
    transpose_f2b_all<<<12288, tb, 0, stream>>>(w_attn, wT_attn, w_proj, wT_proj,
                                                w_fc, wT_fc, w_mlp, wT_mlp);

    // h = LN1(x)
    ln_kernel<<<M, 256, 0, stream>>>(x, ln1_g, ln1_b, h);

    // qkv = h @ w_attn + b_attn   [8192, 3072]
    gemm8p<0, bf16, 128><<<dim3(32, 24, 1), 512, 0, stream>>>(
        h, 1024, 0, wT_attn, 1024, 0, qkv, 3072, 0, b_attn, nullptr, 0, 1.0f, 1024);

    // vT[b] = v[b]^T   (v = qkv cols [2C,3C))
    transpose_b2b<<<dim3(1024 / 32, 2048 / 32, B_DIM), tb, 0, stream>>>(
        qkv + 2 * C_DIM, 3072, (long long)T_DIM * 3072, vT, (long long)C_DIM * T_DIM, T_DIM);

    // S[b] = q[b] @ k[b]^T * (1/32)   [2048, 2048] bf16
    gemm8p<0, bf16, 256><<<dim3(8, 8, B_DIM), 512, 0, stream>>>(
        qkv, 3072, (long long)T_DIM * 3072,
        qkv + C_DIM, 3072, (long long)T_DIM * 3072,
        S, 2048, (long long)T_DIM * T_DIM, nullptr, nullptr, 0, 0.03125f, 1024);

    // P = softmax(S) rows
    softmax_kernel<<<B_DIM * T_DIM, 256, 0, stream>>>(S, P);

    // y[b] = P[b] @ v[b]   [2048, 1024] bf16
    gemm8p<0, bf16, 128><<<dim3(8, 8, B_DIM), 512, 0, stream>>>(
        P, 2048, (long long)T_DIM * T_DIM,
        vT, 2048, (long long)C_DIM * T_DIM,
        y, 1024, (long long)T_DIM * C_DIM, nullptr, nullptr, 0, 1.0f, 2048);

    // x2 = y @ w_proj + b_proj + x   [8192, 1024] fp32
    gemm8p<2, float, 128><<<dim3(32, 8, 1), 512, 0, stream>>>(
        y, 1024, 0, wT_proj, 1024, 0, x2, 1024, 0, b_proj, x, 0, 1.0f, 1024);

    // h2 = LN2(x2)  (reuse h buffer)
    ln_kernel<<<M, 256, 0, stream>>>(x2, ln2_g, ln2_b, h);

    // act = gelu(h2 @ w_fc + b_fc)   [8192, 4096] bf16
    gemm8p<1, bf16, 256><<<dim3(32, 16, 1), 512, 0, stream>>>(
        h, 1024, 0, wT_fc, 1024, 0, act, 4096, 0, b_fc, nullptr, 0, 1.0f, 1024);

    // out = act @ w_mlp_proj + b_mlp_proj + x2   [8192, 1024] fp32
    gemm8p<2, float, 128><<<dim3(32, 8, 1), 512, 0, stream>>>(
        act, 4096, 0, wT_mlp, 4096, 0, out, 1024, 0, b_mlp, x2, 0, 1.0f, 4096);
}